// Round 1
// baseline (1650.384 us; speedup 1.0000x reference)
//
#include <hip/hip_runtime.h>
#include <cstdint>
#include <cstddef>

#define N_NODES 100000
#define N_EDGES 3200000
#define IN_FEAT 512
#define HIDDEN  256
#define N_CLASS 40

// ---------------------------------------------------------------------------
// Workspace layout (bytes), all 256B-aligned
//   support1 : N_NODES*HIDDEN f32   = 102,400,000
//   h        : N_NODES*HIDDEN f32   = 102,400,000
//   support2 : N_NODES*N_CLASS f32  =  16,000,000
//   rptr     : (N_NODES+1) i32      ->    400,128 padded
//   counts   : N_NODES i32          ->    400,128 padded
//   work     : N_NODES i32          ->    400,128 padded
//   scol     : N_EDGES i32          =  12,800,000
//   sval     : N_EDGES f32          =  12,800,000
//   bsums    : 128 i32              ->        512
//   boffs    : 128 i32              ->        512
// total ~247.6 MB
// ---------------------------------------------------------------------------
#define OFF_SUPPORT1 ((size_t)0)
#define OFF_H        ((size_t)102400000)
#define OFF_SUPPORT2 ((size_t)204800000)
#define OFF_RPTR     ((size_t)220800000)
#define OFF_COUNTS   ((size_t)221200128)
#define OFF_WORK     ((size_t)221600256)
#define OFF_SCOL     ((size_t)222000384)
#define OFF_SVAL     ((size_t)234800384)
#define OFF_BSUMS    ((size_t)247600384)
#define OFF_BOFFS    ((size_t)247600896)

// ---------------------------- CSR build ------------------------------------
__global__ void k_hist(const int* __restrict__ erow, int* __restrict__ counts) {
  int i = blockIdx.x * blockDim.x + threadIdx.x;
  int stride = gridDim.x * blockDim.x;
  for (; i < N_EDGES; i += stride) atomicAdd(&counts[erow[i]], 1);
}

// chunk = 1024 nodes per block (256 thr x 4). Writes chunk-local exclusive
// scan into rptr, chunk total into bsums.
__global__ void k_scan1(const int* __restrict__ counts, int* __restrict__ rptr,
                        int* __restrict__ bsums) {
  __shared__ int s[256];
  int b = blockIdx.x, t = threadIdx.x;
  int base = b * 1024 + t * 4;
  int v0 = (base + 0 < N_NODES) ? counts[base + 0] : 0;
  int v1 = (base + 1 < N_NODES) ? counts[base + 1] : 0;
  int v2 = (base + 2 < N_NODES) ? counts[base + 2] : 0;
  int v3 = (base + 3 < N_NODES) ? counts[base + 3] : 0;
  int sum = v0 + v1 + v2 + v3;
  s[t] = sum;
  __syncthreads();
  for (int off = 1; off < 256; off <<= 1) {
    int y = (t >= off) ? s[t - off] : 0;
    __syncthreads();
    s[t] += y;
    __syncthreads();
  }
  int excl = s[t] - sum;  // exclusive prefix of this thread within chunk
  if (base + 0 < N_NODES) rptr[base + 0] = excl; excl += v0;
  if (base + 1 < N_NODES) rptr[base + 1] = excl; excl += v1;
  if (base + 2 < N_NODES) rptr[base + 2] = excl; excl += v2;
  if (base + 3 < N_NODES) rptr[base + 3] = excl;
  if (t == 0) bsums[b] = s[255];
}

#define N_CHUNKS 98  // ceil(100000/1024)
__global__ void k_scan2(const int* __restrict__ bsums, int* __restrict__ boffs) {
  __shared__ int s[128];
  int t = threadIdx.x;
  int v = (t < N_CHUNKS) ? bsums[t] : 0;
  s[t] = v;
  __syncthreads();
  for (int off = 1; off < 128; off <<= 1) {
    int y = (t >= off) ? s[t - off] : 0;
    __syncthreads();
    s[t] += y;
    __syncthreads();
  }
  if (t < N_CHUNKS) boffs[t] = s[t] - v;  // exclusive
}

__global__ void k_scan3(int* __restrict__ rptr, const int* __restrict__ boffs,
                        int* __restrict__ work) {
  int i = blockIdx.x * blockDim.x + threadIdx.x;
  if (i < N_NODES) {
    int r = rptr[i] + boffs[i >> 10];
    rptr[i] = r;
    work[i] = r;
  }
  if (i == 0) rptr[N_NODES] = N_EDGES;
}

__global__ void k_scatter(const int* __restrict__ erow, const int* __restrict__ ecol,
                          const float* __restrict__ eval, int* __restrict__ work,
                          int* __restrict__ scol, float* __restrict__ sval) {
  int i = blockIdx.x * blockDim.x + threadIdx.x;
  int stride = gridDim.x * blockDim.x;
  for (; i < N_EDGES; i += stride) {
    int r = erow[i];
    int p = atomicAdd(&work[r], 1);
    scol[p] = ecol[i];
    sval[p] = eval[i];
  }
}

// ------------------------- GEMM1: support1 = X @ W1 -------------------------
// M=100000, K=512, N=256. 128x64 tile, 256 threads, each 8x4 outputs.
__global__ __launch_bounds__(256) void k_gemm1(const float* __restrict__ X,
                                               const float* __restrict__ W,
                                               float* __restrict__ C) {
  __shared__ __align__(16) float As[16][132];  // [k][m], padded stride 132
  __shared__ __align__(16) float Bs[16][64];   // [k][n]
  const int t = threadIdx.x;
  const int tx = t & 15;        // n-group (4 cols)
  const int ty = t >> 4;        // m-group (8 rows)
  const int m0 = blockIdx.y * 128;
  const int n0 = blockIdx.x * 64;

  float acc[8][4];
#pragma unroll
  for (int i = 0; i < 8; i++)
#pragma unroll
    for (int j = 0; j < 4; j++) acc[i][j] = 0.f;

  for (int k0 = 0; k0 < IN_FEAT; k0 += 16) {
    // load A-tile 128x16 (512 float4s, 2 per thread), store transposed
#pragma unroll
    for (int i = 0; i < 2; i++) {
      int q = t + i * 256;        // float4 index 0..511
      int mm = q >> 2;            // 0..127
      int kv = (q & 3) * 4;       // 0,4,8,12
      int row = m0 + mm;
      if (row > N_NODES - 1) row = N_NODES - 1;
      float4 a = *(const float4*)&X[(size_t)row * IN_FEAT + k0 + kv];
      As[kv + 0][mm] = a.x;
      As[kv + 1][mm] = a.y;
      As[kv + 2][mm] = a.z;
      As[kv + 3][mm] = a.w;
    }
    // load B-tile 16x64 (256 float4s, 1 per thread)
    {
      int kk = t >> 4;
      int nv = (t & 15) * 4;
      float4 bb = *(const float4*)&W[(size_t)(k0 + kk) * HIDDEN + n0 + nv];
      *(float4*)&Bs[kk][nv] = bb;
    }
    __syncthreads();
#pragma unroll
    for (int kk = 0; kk < 16; kk++) {
      float4 a0 = *(const float4*)&As[kk][ty * 8];
      float4 a1 = *(const float4*)&As[kk][ty * 8 + 4];
      float4 bb = *(const float4*)&Bs[kk][tx * 4];
      float av[8] = {a0.x, a0.y, a0.z, a0.w, a1.x, a1.y, a1.z, a1.w};
      float bv[4] = {bb.x, bb.y, bb.z, bb.w};
#pragma unroll
      for (int i = 0; i < 8; i++)
#pragma unroll
        for (int j = 0; j < 4; j++) acc[i][j] += av[i] * bv[j];
    }
    __syncthreads();
  }
#pragma unroll
  for (int i = 0; i < 8; i++) {
    int row = m0 + ty * 8 + i;
    if (row < N_NODES) {
      float4 o = {acc[i][0], acc[i][1], acc[i][2], acc[i][3]};
      *(float4*)&C[(size_t)row * HIDDEN + n0 + tx * 4] = o;
    }
  }
}

// ---------------- SpMM1: h = relu(A @ support1 + b1) ------------------------
// one block (256 thr) per node; lane = feature
__global__ __launch_bounds__(256) void k_spmm1(const float* __restrict__ S,
                                               const int* __restrict__ rptr,
                                               const int* __restrict__ scol,
                                               const float* __restrict__ sval,
                                               const float* __restrict__ b1,
                                               float* __restrict__ H) {
  const int n = blockIdx.x;
  const int f = threadIdx.x;
  __shared__ int cs[256];
  __shared__ float vs[256];
  int e0 = rptr[n], e1 = rptr[n + 1];
  float a0 = 0.f, a1 = 0.f, a2 = 0.f, a3 = 0.f;
  for (int base = e0; base < e1; base += 256) {
    int cnt = min(256, e1 - base);
    if (f < cnt) {
      cs[f] = scol[base + f];
      vs[f] = sval[base + f];
    }
    __syncthreads();
    int j = 0;
    for (; j + 4 <= cnt; j += 4) {
      a0 += vs[j + 0] * S[cs[j + 0] * HIDDEN + f];
      a1 += vs[j + 1] * S[cs[j + 1] * HIDDEN + f];
      a2 += vs[j + 2] * S[cs[j + 2] * HIDDEN + f];
      a3 += vs[j + 3] * S[cs[j + 3] * HIDDEN + f];
    }
    for (; j < cnt; j++) a0 += vs[j] * S[cs[j] * HIDDEN + f];
    __syncthreads();
  }
  float r = a0 + a1 + a2 + a3 + b1[f];
  H[(size_t)n * HIDDEN + f] = fmaxf(r, 0.f);
}

// --------------------- GEMM2: support2 = H @ W2 -----------------------------
// block = 256 threads = 256 rows; W2 (256x40) fully in LDS; H staged in chunks
__global__ __launch_bounds__(256) void k_gemm2(const float* __restrict__ H,
                                               const float* __restrict__ W2,
                                               float* __restrict__ S2) {
  __shared__ __align__(16) float Ws[HIDDEN][N_CLASS];  // 40 KB
  __shared__ float Hs[256][33];                        // 33.8 KB, pad for banks
  const int t = threadIdx.x;
  const int r0 = blockIdx.x * 256;

  // load W2: 2560 float4s, 10 per thread
#pragma unroll
  for (int i = 0; i < 10; i++) {
    int q = t + i * 256;  // float4 index
    float4 w = *(const float4*)&W2[(size_t)q * 4];
    *(float4*)&((float*)Ws)[(size_t)q * 4] = w;
  }

  float acc[N_CLASS];
#pragma unroll
  for (int n = 0; n < N_CLASS; n++) acc[n] = 0.f;

  for (int kc = 0; kc < HIDDEN; kc += 32) {
    __syncthreads();
    // stage H rows r0..r0+255, k = kc..kc+31  (2048 float4s, 8/thread)
#pragma unroll
    for (int i = 0; i < 8; i++) {
      int q = t + i * 256;
      int row = q >> 3;            // 0..255
      int kv = (q & 7) * 4;        // 0..28
      int grow = r0 + row;
      if (grow > N_NODES - 1) grow = N_NODES - 1;
      float4 hv = *(const float4*)&H[(size_t)grow * HIDDEN + kc + kv];
      Hs[row][kv + 0] = hv.x;
      Hs[row][kv + 1] = hv.y;
      Hs[row][kv + 2] = hv.z;
      Hs[row][kv + 3] = hv.w;
    }
    __syncthreads();
    const float4* Wsv = (const float4*)Ws;
#pragma unroll
    for (int k = 0; k < 32; k++) {
      float hk = Hs[t][k];
      int kg = kc + k;
#pragma unroll
      for (int n4 = 0; n4 < 10; n4++) {
        float4 w = Wsv[kg * 10 + n4];
        acc[n4 * 4 + 0] += hk * w.x;
        acc[n4 * 4 + 1] += hk * w.y;
        acc[n4 * 4 + 2] += hk * w.z;
        acc[n4 * 4 + 3] += hk * w.w;
      }
    }
  }
  int row = r0 + t;
  if (row < N_NODES) {
#pragma unroll
    for (int n4 = 0; n4 < 10; n4++) {
      float4 o = {acc[n4 * 4 + 0], acc[n4 * 4 + 1], acc[n4 * 4 + 2], acc[n4 * 4 + 3]};
      *(float4*)&S2[(size_t)row * N_CLASS + n4 * 4] = o;
    }
  }
}

// --------- SpMM2 + bias + log_softmax: out = lsm(A @ support2 + b2) ---------
// one wave per node, lanes 0..39 = classes
__global__ __launch_bounds__(256) void k_spmm2(const float* __restrict__ S2,
                                               const int* __restrict__ rptr,
                                               const int* __restrict__ scol,
                                               const float* __restrict__ sval,
                                               const float* __restrict__ b2,
                                               float* __restrict__ out) {
  const int wid = (blockIdx.x * blockDim.x + threadIdx.x) >> 6;  // node
  const int lane = threadIdx.x & 63;
  const bool act = lane < N_CLASS;
  const int f = act ? lane : 0;
  int e0 = rptr[wid], e1 = rptr[wid + 1];
  float acc = 0.f;
  for (int base = e0; base < e1; base += 64) {
    int rem = min(64, e1 - base);
    int c = 0;
    float v = 0.f;
    if (lane < rem) {
      c = scol[base + lane];
      v = sval[base + lane];
    }
    for (int j = 0; j < rem; j++) {
      int cj = __shfl(c, j);
      float vj = __shfl(v, j);
      if (act) acc += vj * S2[cj * N_CLASS + f];
    }
  }
  float x = act ? (acc + b2[f]) : -INFINITY;
  // wave max
  float m = x;
#pragma unroll
  for (int o = 32; o > 0; o >>= 1) m = fmaxf(m, __shfl_xor(m, o));
  float ex = act ? expf(x - m) : 0.f;
  float s = ex;
#pragma unroll
  for (int o = 32; o > 0; o >>= 1) s += __shfl_xor(s, o);
  if (act) out[(size_t)wid * N_CLASS + lane] = (x - m) - logf(s);
}

// ---------------------------------------------------------------------------
extern "C" void kernel_launch(void* const* d_in, const int* in_sizes, int n_in,
                              void* d_out, int out_size, void* d_ws, size_t ws_size,
                              hipStream_t stream) {
  const float* x    = (const float*)d_in[0];
  const float* w1   = (const float*)d_in[1];
  const float* b1   = (const float*)d_in[2];
  const float* w2   = (const float*)d_in[3];
  const float* b2   = (const float*)d_in[4];
  const float* eval = (const float*)d_in[5];
  const int*   erow = (const int*)d_in[6];
  const int*   ecol = (const int*)d_in[7];
  float* out = (float*)d_out;

  char* ws = (char*)d_ws;
  float* support1 = (float*)(ws + OFF_SUPPORT1);
  float* h        = (float*)(ws + OFF_H);
  float* support2 = (float*)(ws + OFF_SUPPORT2);
  int*   rptr     = (int*)(ws + OFF_RPTR);
  int*   counts   = (int*)(ws + OFF_COUNTS);
  int*   work     = (int*)(ws + OFF_WORK);
  int*   scol     = (int*)(ws + OFF_SCOL);
  float* sval     = (float*)(ws + OFF_SVAL);
  int*   bsums    = (int*)(ws + OFF_BSUMS);
  int*   boffs    = (int*)(ws + OFF_BOFFS);

  // ---- CSR build ----
  hipMemsetAsync(counts, 0, (size_t)N_NODES * 4, stream);
  k_hist<<<1024, 256, 0, stream>>>(erow, counts);
  k_scan1<<<N_CHUNKS, 256, 0, stream>>>(counts, rptr, bsums);
  k_scan2<<<1, 128, 0, stream>>>(bsums, boffs);
  k_scan3<<<(N_NODES + 255) / 256, 256, 0, stream>>>(rptr, boffs, work);
  k_scatter<<<1024, 256, 0, stream>>>(erow, ecol, eval, work, scol, sval);

  // ---- layer 1 ----
  k_gemm1<<<dim3(HIDDEN / 64, (N_NODES + 127) / 128), 256, 0, stream>>>(x, w1, support1);
  k_spmm1<<<N_NODES, 256, 0, stream>>>(support1, rptr, scol, sval, b1, h);

  // ---- layer 2 ----
  k_gemm2<<<(N_NODES + 255) / 256, 256, 0, stream>>>(h, w2, support2);
  k_spmm2<<<N_NODES / 4, 256, 0, stream>>>(support2, rptr, scol, sval, b2, out);
}

// Round 2
// 1209.823 us; speedup vs baseline: 1.3642x; 1.3642x over previous
//
#include <hip/hip_runtime.h>
#include <cstdint>
#include <cstddef>

#define N_NODES 100000
#define N_EDGES 3200000
#define IN_FEAT 512
#define HIDDEN  256
#define N_CLASS 40

// ---------------------------------------------------------------------------
// Workspace layout (bytes), 256B-aligned
//   support1 : N_NODES*HIDDEN bf16 =  51,200,000
//   h        : N_NODES*HIDDEN f32  = 102,400,000
//   support2 : N_NODES*N_CLASS f32 =  16,000,000
//   w1t      : HIDDEN x IN_FEAT bf16 (transposed W1) = 262,144
//   rptr/counts/work : i32 each 400,128
//   sedge    : N_EDGES int2 (col, val-bits) = 25,600,000
//   bsums/boffs : 512 each
// total ~196.7 MB
// ---------------------------------------------------------------------------
#define OFF_SUPPORT1 ((size_t)0)
#define OFF_H        ((size_t)51200000)
#define OFF_SUPPORT2 ((size_t)153600000)
#define OFF_W1T      ((size_t)169600000)
#define OFF_RPTR     ((size_t)169862144)
#define OFF_COUNTS   ((size_t)170262272)
#define OFF_WORK     ((size_t)170662400)
#define OFF_SEDGE    ((size_t)171062528)
#define OFF_BSUMS    ((size_t)196662528)
#define OFF_BOFFS    ((size_t)196663040)

typedef __attribute__((ext_vector_type(8))) short short8x;
typedef __attribute__((ext_vector_type(4))) float f32x4;

static __device__ __forceinline__ unsigned short f2bf(float f) {
  unsigned u = __float_as_uint(f);
  unsigned r = (u + 0x7FFFu + ((u >> 16) & 1u)) >> 16;  // RNE
  return (unsigned short)r;
}
static __device__ __forceinline__ float bf2f(unsigned short s) {
  return __uint_as_float(((unsigned)s) << 16);
}

// ---------------------------- CSR build ------------------------------------
__global__ void k_hist(const int* __restrict__ erow, int* __restrict__ counts) {
  int i = blockIdx.x * blockDim.x + threadIdx.x;
  int stride = gridDim.x * blockDim.x;
  for (; i < N_EDGES; i += stride) atomicAdd(&counts[erow[i]], 1);
}

__global__ void k_scan1(const int* __restrict__ counts, int* __restrict__ rptr,
                        int* __restrict__ bsums) {
  __shared__ int s[256];
  int b = blockIdx.x, t = threadIdx.x;
  int base = b * 1024 + t * 4;
  int v0 = (base + 0 < N_NODES) ? counts[base + 0] : 0;
  int v1 = (base + 1 < N_NODES) ? counts[base + 1] : 0;
  int v2 = (base + 2 < N_NODES) ? counts[base + 2] : 0;
  int v3 = (base + 3 < N_NODES) ? counts[base + 3] : 0;
  int sum = v0 + v1 + v2 + v3;
  s[t] = sum;
  __syncthreads();
  for (int off = 1; off < 256; off <<= 1) {
    int y = (t >= off) ? s[t - off] : 0;
    __syncthreads();
    s[t] += y;
    __syncthreads();
  }
  int excl = s[t] - sum;
  if (base + 0 < N_NODES) rptr[base + 0] = excl; excl += v0;
  if (base + 1 < N_NODES) rptr[base + 1] = excl; excl += v1;
  if (base + 2 < N_NODES) rptr[base + 2] = excl; excl += v2;
  if (base + 3 < N_NODES) rptr[base + 3] = excl;
  if (t == 0) bsums[b] = s[255];
}

#define N_CHUNKS 98
__global__ void k_scan2(const int* __restrict__ bsums, int* __restrict__ boffs) {
  __shared__ int s[128];
  int t = threadIdx.x;
  int v = (t < N_CHUNKS) ? bsums[t] : 0;
  s[t] = v;
  __syncthreads();
  for (int off = 1; off < 128; off <<= 1) {
    int y = (t >= off) ? s[t - off] : 0;
    __syncthreads();
    s[t] += y;
    __syncthreads();
  }
  if (t < N_CHUNKS) boffs[t] = s[t] - v;
}

__global__ void k_scan3(int* __restrict__ rptr, const int* __restrict__ boffs,
                        int* __restrict__ work) {
  int i = blockIdx.x * blockDim.x + threadIdx.x;
  if (i < N_NODES) {
    int r = rptr[i] + boffs[i >> 10];
    rptr[i] = r;
    work[i] = r;
  }
  if (i == 0) rptr[N_NODES] = N_EDGES;
}

__global__ void k_scatter(const int* __restrict__ erow, const int* __restrict__ ecol,
                          const float* __restrict__ eval, int* __restrict__ work,
                          int2* __restrict__ sedge) {
  int i = blockIdx.x * blockDim.x + threadIdx.x;
  int stride = gridDim.x * blockDim.x;
  for (; i < N_EDGES; i += stride) {
    int r = erow[i];
    int p = atomicAdd(&work[r], 1);
    sedge[p] = make_int2(ecol[i], __float_as_int(eval[i]));
  }
}

// ------------------- W1 (512x256 f32) -> W1t (256x512 bf16) -----------------
__global__ __launch_bounds__(256) void k_prep_w(const float* __restrict__ W,
                                                unsigned short* __restrict__ Wt) {
  int tid = blockIdx.x * 256 + threadIdx.x;  // 131072 total
  int n = tid & 255;
  int k = tid >> 8;
  Wt[(size_t)n * IN_FEAT + k] = f2bf(W[(size_t)k * HIDDEN + n]);
}

// ------------------- GEMM1 (MFMA): support1 = bf16(X @ W1) ------------------
// M=100000, N=256, K=512. 128x128 block tile, 4 waves of 64x64, BK=32.
// A = X fp32 (cast to bf16 during staging), B = W1t bf16 (N-major, K contig).
__global__ __launch_bounds__(256) void k_gemm1(const float* __restrict__ X,
                                               const unsigned short* __restrict__ Wt,
                                               unsigned short* __restrict__ C) {
  __shared__ short As[128 * 32];  // [m][k], 64B rows
  __shared__ short Bs[128 * 32];  // [n][k]
  const int t = threadIdx.x;
  const int wave = t >> 6, lane = t & 63;
  const int q = lane >> 4, r = lane & 15;
  const int wm = (wave >> 1) * 64, wn = (wave & 1) * 64;
  const int m0 = blockIdx.x * 128;
  const int n0 = blockIdx.y * 128;

  f32x4 acc[4][4];
#pragma unroll
  for (int mi = 0; mi < 4; mi++)
#pragma unroll
    for (int ni = 0; ni < 4; ni++) acc[mi][ni] = (f32x4){0.f, 0.f, 0.f, 0.f};

  for (int k0 = 0; k0 < IN_FEAT; k0 += 32) {
    // stage A: 128 rows x 32 k, cast fp32->bf16. 512 chunks of 8 bf16.
#pragma unroll
    for (int i = 0; i < 2; i++) {
      int cidx = t + i * 256;
      int row = cidx >> 2;
      int ko = (cidx & 3) * 8;
      int gr = m0 + row;
      if (gr > N_NODES - 1) gr = N_NODES - 1;
      const float4* src = (const float4*)&X[(size_t)gr * IN_FEAT + k0 + ko];
      float4 x0 = src[0], x1 = src[1];
      short8x a;
      a[0] = (short)f2bf(x0.x); a[1] = (short)f2bf(x0.y);
      a[2] = (short)f2bf(x0.z); a[3] = (short)f2bf(x0.w);
      a[4] = (short)f2bf(x1.x); a[5] = (short)f2bf(x1.y);
      a[6] = (short)f2bf(x1.z); a[7] = (short)f2bf(x1.w);
      *(short8x*)&As[row * 32 + ko] = a;
    }
    // stage B: 128 n-rows x 32 k from Wt (already bf16, contiguous in k)
#pragma unroll
    for (int i = 0; i < 2; i++) {
      int cidx = t + i * 256;
      int row = cidx >> 2;
      int ko = (cidx & 3) * 8;
      short8x b = *(const short8x*)&Wt[(size_t)(n0 + row) * IN_FEAT + k0 + ko];
      *(short8x*)&Bs[row * 32 + ko] = b;
    }
    __syncthreads();
    short8x af[4], bf[4];
#pragma unroll
    for (int mi = 0; mi < 4; mi++)
      af[mi] = *(const short8x*)&As[(wm + mi * 16 + r) * 32 + q * 8];
#pragma unroll
    for (int ni = 0; ni < 4; ni++)
      bf[ni] = *(const short8x*)&Bs[(wn + ni * 16 + r) * 32 + q * 8];
#pragma unroll
    for (int mi = 0; mi < 4; mi++)
#pragma unroll
      for (int ni = 0; ni < 4; ni++)
        acc[mi][ni] = __builtin_amdgcn_mfma_f32_16x16x32_bf16(af[mi], bf[ni],
                                                              acc[mi][ni], 0, 0, 0);
    __syncthreads();
  }
  // epilogue: C/D layout col=lane&15, row=(lane>>4)*4+reg
#pragma unroll
  for (int mi = 0; mi < 4; mi++) {
#pragma unroll
    for (int ni = 0; ni < 4; ni++) {
#pragma unroll
      for (int reg = 0; reg < 4; reg++) {
        int row = m0 + wm + mi * 16 + q * 4 + reg;
        int col = n0 + wn + ni * 16 + r;
        if (row < N_NODES)
          C[(size_t)row * HIDDEN + col] = f2bf(acc[mi][ni][reg]);
      }
    }
  }
}

// ---------------- SpMM1: h = relu(A @ support1 + b1), fp32 out --------------
// one wave per node; lane handles 4 features via ushort4 (bf16x4) loads
__global__ __launch_bounds__(256) void k_spmm1(const unsigned short* __restrict__ S,
                                               const int* __restrict__ rptr,
                                               const int2* __restrict__ sedge,
                                               const float* __restrict__ b1,
                                               float* __restrict__ H) {
  const int wid = (blockIdx.x * blockDim.x + threadIdx.x) >> 6;  // node
  const int lane = threadIdx.x & 63;
  int e0 = rptr[wid], e1 = rptr[wid + 1];
  float a0 = 0.f, a1 = 0.f, a2 = 0.f, a3 = 0.f;
  for (int base = e0; base < e1; base += 64) {
    int rem = min(64, e1 - base);
    int c = 0;
    float v = 0.f;
    if (lane < rem) {
      int2 e = sedge[base + lane];
      c = e.x;
      v = __int_as_float(e.y);
    }
    for (int j = 0; j < rem; j++) {
      int cj = __shfl(c, j);
      float vj = __shfl(v, j);
      ushort4 s4 = *(const ushort4*)&S[(size_t)cj * HIDDEN + lane * 4];
      a0 += vj * bf2f(s4.x);
      a1 += vj * bf2f(s4.y);
      a2 += vj * bf2f(s4.z);
      a3 += vj * bf2f(s4.w);
    }
  }
  const float4 bb = *(const float4*)&b1[lane * 4];
  float4 o;
  o.x = fmaxf(a0 + bb.x, 0.f);
  o.y = fmaxf(a1 + bb.y, 0.f);
  o.z = fmaxf(a2 + bb.z, 0.f);
  o.w = fmaxf(a3 + bb.w, 0.f);
  *(float4*)&H[(size_t)wid * HIDDEN + lane * 4] = o;
}

// --------------------- GEMM2: support2 = H @ W2 -----------------------------
__global__ __launch_bounds__(256) void k_gemm2(const float* __restrict__ H,
                                               const float* __restrict__ W2,
                                               float* __restrict__ S2) {
  __shared__ __align__(16) float Ws[HIDDEN][N_CLASS];  // 40 KB
  __shared__ float Hs[256][33];
  const int t = threadIdx.x;
  const int r0 = blockIdx.x * 256;

#pragma unroll
  for (int i = 0; i < 10; i++) {
    int qq = t + i * 256;
    float4 w = *(const float4*)&W2[(size_t)qq * 4];
    *(float4*)&((float*)Ws)[(size_t)qq * 4] = w;
  }

  float acc[N_CLASS];
#pragma unroll
  for (int n = 0; n < N_CLASS; n++) acc[n] = 0.f;

  for (int kc = 0; kc < HIDDEN; kc += 32) {
    __syncthreads();
#pragma unroll
    for (int i = 0; i < 8; i++) {
      int qq = t + i * 256;
      int row = qq >> 3;
      int kv = (qq & 7) * 4;
      int grow = r0 + row;
      if (grow > N_NODES - 1) grow = N_NODES - 1;
      float4 hv = *(const float4*)&H[(size_t)grow * HIDDEN + kc + kv];
      Hs[row][kv + 0] = hv.x;
      Hs[row][kv + 1] = hv.y;
      Hs[row][kv + 2] = hv.z;
      Hs[row][kv + 3] = hv.w;
    }
    __syncthreads();
    const float4* Wsv = (const float4*)Ws;
#pragma unroll
    for (int k = 0; k < 32; k++) {
      float hk = Hs[t][k];
      int kg = kc + k;
#pragma unroll
      for (int n4 = 0; n4 < 10; n4++) {
        float4 w = Wsv[kg * 10 + n4];
        acc[n4 * 4 + 0] += hk * w.x;
        acc[n4 * 4 + 1] += hk * w.y;
        acc[n4 * 4 + 2] += hk * w.z;
        acc[n4 * 4 + 3] += hk * w.w;
      }
    }
  }
  int row = r0 + t;
  if (row < N_NODES) {
#pragma unroll
    for (int n4 = 0; n4 < 10; n4++) {
      float4 o = {acc[n4 * 4 + 0], acc[n4 * 4 + 1], acc[n4 * 4 + 2], acc[n4 * 4 + 3]};
      *(float4*)&S2[(size_t)row * N_CLASS + n4 * 4] = o;
    }
  }
}

// --------- SpMM2 + bias + log_softmax -------------------------------------
__global__ __launch_bounds__(256) void k_spmm2(const float* __restrict__ S2,
                                               const int* __restrict__ rptr,
                                               const int2* __restrict__ sedge,
                                               const float* __restrict__ b2,
                                               float* __restrict__ out) {
  const int wid = (blockIdx.x * blockDim.x + threadIdx.x) >> 6;
  const int lane = threadIdx.x & 63;
  const bool act = lane < N_CLASS;
  const int f = act ? lane : 0;
  int e0 = rptr[wid], e1 = rptr[wid + 1];
  float acc = 0.f;
  for (int base = e0; base < e1; base += 64) {
    int rem = min(64, e1 - base);
    int c = 0;
    float v = 0.f;
    if (lane < rem) {
      int2 e = sedge[base + lane];
      c = e.x;
      v = __int_as_float(e.y);
    }
    for (int j = 0; j < rem; j++) {
      int cj = __shfl(c, j);
      float vj = __shfl(v, j);
      if (act) acc += vj * S2[(size_t)cj * N_CLASS + f];
    }
  }
  float x = act ? (acc + b2[f]) : -INFINITY;
  float m = x;
#pragma unroll
  for (int o = 32; o > 0; o >>= 1) m = fmaxf(m, __shfl_xor(m, o));
  float ex = act ? expf(x - m) : 0.f;
  float s = ex;
#pragma unroll
  for (int o = 32; o > 0; o >>= 1) s += __shfl_xor(s, o);
  if (act) out[(size_t)wid * N_CLASS + lane] = (x - m) - logf(s);
}

// ---------------------------------------------------------------------------
extern "C" void kernel_launch(void* const* d_in, const int* in_sizes, int n_in,
                              void* d_out, int out_size, void* d_ws, size_t ws_size,
                              hipStream_t stream) {
  const float* x    = (const float*)d_in[0];
  const float* w1   = (const float*)d_in[1];
  const float* b1   = (const float*)d_in[2];
  const float* w2   = (const float*)d_in[3];
  const float* b2   = (const float*)d_in[4];
  const float* eval = (const float*)d_in[5];
  const int*   erow = (const int*)d_in[6];
  const int*   ecol = (const int*)d_in[7];
  float* out = (float*)d_out;

  char* ws = (char*)d_ws;
  unsigned short* support1 = (unsigned short*)(ws + OFF_SUPPORT1);
  float* h        = (float*)(ws + OFF_H);
  float* support2 = (float*)(ws + OFF_SUPPORT2);
  unsigned short* w1t = (unsigned short*)(ws + OFF_W1T);
  int*   rptr     = (int*)(ws + OFF_RPTR);
  int*   counts   = (int*)(ws + OFF_COUNTS);
  int*   work     = (int*)(ws + OFF_WORK);
  int2*  sedge    = (int2*)(ws + OFF_SEDGE);
  int*   bsums    = (int*)(ws + OFF_BSUMS);
  int*   boffs    = (int*)(ws + OFF_BOFFS);

  // ---- CSR build + weight prep ----
  hipMemsetAsync(counts, 0, (size_t)N_NODES * 4, stream);
  k_prep_w<<<512, 256, 0, stream>>>(w1, w1t);
  k_hist<<<1024, 256, 0, stream>>>(erow, counts);
  k_scan1<<<N_CHUNKS, 256, 0, stream>>>(counts, rptr, bsums);
  k_scan2<<<1, 128, 0, stream>>>(bsums, boffs);
  k_scan3<<<(N_NODES + 255) / 256, 256, 0, stream>>>(rptr, boffs, work);
  k_scatter<<<1024, 256, 0, stream>>>(erow, ecol, eval, work, sedge);

  // ---- layer 1 ----
  k_gemm1<<<dim3((N_NODES + 127) / 128, HIDDEN / 128), 256, 0, stream>>>(x, w1t, support1);
  k_spmm1<<<N_NODES / 4, 256, 0, stream>>>(support1, rptr, sedge, b1, h);

  // ---- layer 2 ----
  k_gemm2<<<(N_NODES + 255) / 256, 256, 0, stream>>>(h, w2, support2);
  k_spmm2<<<N_NODES / 4, 256, 0, stream>>>(support2, rptr, sedge, b2, out);
}

// Round 3
// 957.017 us; speedup vs baseline: 1.7245x; 1.2642x over previous
//
#include <hip/hip_runtime.h>
#include <cstdint>
#include <cstddef>

#define N_NODES 100000
#define N_EDGES 3200000
#define IN_FEAT 512
#define HIDDEN  256
#define N_CLASS 40

#define N_BUCKETS 196        // ceil(100000 / 512), bucket = row >> 9
#define SC_CHUNK 4096        // edges per binscatter block (256 thr x 16)
#define N_SC_BLOCKS 782      // ceil(3.2e6 / 4096)

// ---------------------------------------------------------------------------
// Workspace layout (bytes), 256B-aligned
//   support1 : N_NODES*HIDDEN bf16  =  51,200,000
//   h        : N_NODES*HIDDEN bf16  =  51,200,000
//   support2 : N_NODES*N_CLASS f32  =  16,000,000
//   w1t      : HIDDEN x IN_FEAT bf16 =    262,144
//   rptr     : (N_NODES+1) i32      ->     400,128
//   bcnt/bbase/bcur : ~196 i32 each ->       1,024 each
//   binned   : N_EDGES int2         =  25,600,000
//   sedge    : N_EDGES int2         =  25,600,000
// total ~170.3 MB
// ---------------------------------------------------------------------------
#define OFF_SUPPORT1 ((size_t)0)
#define OFF_H        ((size_t)51200000)
#define OFF_SUPPORT2 ((size_t)102400000)
#define OFF_W1T      ((size_t)118400000)
#define OFF_RPTR     ((size_t)118662144)
#define OFF_BCNT     ((size_t)119062272)
#define OFF_BBASE    ((size_t)119063296)
#define OFF_BCUR     ((size_t)119064320)
#define OFF_BINNED   ((size_t)119065344)
#define OFF_SEDGE    ((size_t)144665344)

typedef __attribute__((ext_vector_type(8))) short short8x;
typedef __attribute__((ext_vector_type(4))) float f32x4;

static __device__ __forceinline__ unsigned short f2bf(float f) {
  unsigned u = __float_as_uint(f);
  unsigned r = (u + 0x7FFFu + ((u >> 16) & 1u)) >> 16;  // RNE
  return (unsigned short)r;
}
static __device__ __forceinline__ float bf2f(unsigned short s) {
  return __uint_as_float(((unsigned)s) << 16);
}

// ----------------------- bucketed CSR build --------------------------------
// Pass 1: per-bucket edge counts via LDS histogram
__global__ __launch_bounds__(256) void k_bincnt(const int* __restrict__ erow,
                                                int* __restrict__ bcnt) {
  __shared__ int lh[256];
  lh[threadIdx.x] = 0;
  __syncthreads();
  int i = blockIdx.x * blockDim.x + threadIdx.x;
  int stride = gridDim.x * blockDim.x;
  for (; i < N_EDGES; i += stride) atomicAdd(&lh[erow[i] >> 9], 1);
  __syncthreads();
  if (threadIdx.x < N_BUCKETS) atomicAdd(&bcnt[threadIdx.x], lh[threadIdx.x]);
}

// Pass 2: scan bucket counts -> bbase (and init cursors)
__global__ __launch_bounds__(256) void k_binscan(const int* __restrict__ bcnt,
                                                 int* __restrict__ bbase,
                                                 int* __restrict__ bcur,
                                                 int* __restrict__ rptr) {
  __shared__ int s[256];
  int t = threadIdx.x;
  int v = (t < N_BUCKETS) ? bcnt[t] : 0;
  s[t] = v;
  __syncthreads();
  for (int off = 1; off < 256; off <<= 1) {
    int y = (t >= off) ? s[t - off] : 0;
    __syncthreads();
    s[t] += y;
    __syncthreads();
  }
  if (t < N_BUCKETS) {
    int e = s[t] - v;
    bbase[t] = e;
    bcur[t] = e;
  }
  if (t == 0) {
    bbase[N_BUCKETS] = N_EDGES;
    rptr[N_NODES] = N_EDGES;
  }
}

// Pass 3: scatter edges into bucket-major order, workgroup-aggregated atomics
__global__ __launch_bounds__(256) void k_binscatter(const int* __restrict__ erow,
                                                    const int* __restrict__ ecol,
                                                    const float* __restrict__ eval,
                                                    int* __restrict__ bcur,
                                                    int2* __restrict__ binned) {
  __shared__ int lcnt[256];
  __shared__ int lcur[256];
  const int t = threadIdx.x;
  const int base = blockIdx.x * SC_CHUNK;
  lcnt[t] = 0;
  __syncthreads();
  int rows[16], cols[16], vals[16];
#pragma unroll
  for (int e = 0; e < 16; e++) {
    int i = base + t + e * 256;
    if (i < N_EDGES) {
      rows[e] = erow[i];
      cols[e] = ecol[i];
      vals[e] = __float_as_int(eval[i]);
      atomicAdd(&lcnt[rows[e] >> 9], 1);
    } else {
      rows[e] = -1;
    }
  }
  __syncthreads();
  if (t < N_BUCKETS) lcur[t] = atomicAdd(&bcur[t], lcnt[t]);
  __syncthreads();
#pragma unroll
  for (int e = 0; e < 16; e++) {
    if (rows[e] >= 0) {
      int bkt = rows[e] >> 9;
      int p = atomicAdd(&lcur[bkt], 1);
      binned[p] = make_int2(((rows[e] & 511) << 17) | cols[e], vals[e]);
    }
  }
}

// Pass 4: per-bucket CSR: count(LDS) -> scan(LDS) -> rptr + in-bucket scatter
__global__ __launch_bounds__(256) void k_bucket_csr(const int2* __restrict__ binned,
                                                    const int* __restrict__ bbase,
                                                    int* __restrict__ rptr,
                                                    int2* __restrict__ sedge) {
  const int b = blockIdx.x;
  const int t = threadIdx.x;
  __shared__ int cnt[512];
  __shared__ int excl[512];
  __shared__ int s[256];
  cnt[t] = 0;
  cnt[t + 256] = 0;
  __syncthreads();
  const int ebase = bbase[b];
  const int ecnt = bbase[b + 1] - ebase;
  for (int i = t; i < ecnt; i += 256)
    atomicAdd(&cnt[((unsigned)binned[ebase + i].x) >> 17], 1);
  __syncthreads();
  int c0 = cnt[2 * t], c1 = cnt[2 * t + 1];
  s[t] = c0 + c1;
  __syncthreads();
  for (int off = 1; off < 256; off <<= 1) {
    int y = (t >= off) ? s[t - off] : 0;
    __syncthreads();
    s[t] += y;
    __syncthreads();
  }
  int e = s[t] - (c0 + c1);
  excl[2 * t] = e;
  excl[2 * t + 1] = e + c0;
  __syncthreads();
  for (int i = t; i < 512; i += 256) {
    int node = b * 512 + i;
    if (node < N_NODES) rptr[node] = ebase + excl[i];
  }
  __syncthreads();  // rptr reads of excl must finish before cursor mutation
  for (int i = t; i < ecnt; i += 256) {
    int2 e2 = binned[ebase + i];
    int lrow = ((unsigned)e2.x) >> 17;
    int col = e2.x & 0x1FFFF;
    int p = atomicAdd(&excl[lrow], 1);
    sedge[ebase + p] = make_int2(col, e2.y);
  }
}

// ------------------- W1 (512x256 f32) -> W1t (256x512 bf16) -----------------
__global__ __launch_bounds__(256) void k_prep_w(const float* __restrict__ W,
                                                unsigned short* __restrict__ Wt) {
  int tid = blockIdx.x * 256 + threadIdx.x;  // 131072 total
  int n = tid & 255;
  int k = tid >> 8;
  Wt[(size_t)n * IN_FEAT + k] = f2bf(W[(size_t)k * HIDDEN + n]);
}

// ------------------- GEMM1 (MFMA): support1 = bf16(X @ W1) ------------------
__global__ __launch_bounds__(256) void k_gemm1(const float* __restrict__ X,
                                               const unsigned short* __restrict__ Wt,
                                               unsigned short* __restrict__ C) {
  __shared__ short As[128 * 32];  // [m][k]
  __shared__ short Bs[128 * 32];  // [n][k]
  const int t = threadIdx.x;
  const int wave = t >> 6, lane = t & 63;
  const int q = lane >> 4, r = lane & 15;
  const int wm = (wave >> 1) * 64, wn = (wave & 1) * 64;
  const int m0 = blockIdx.x * 128;
  const int n0 = blockIdx.y * 128;

  f32x4 acc[4][4];
#pragma unroll
  for (int mi = 0; mi < 4; mi++)
#pragma unroll
    for (int ni = 0; ni < 4; ni++) acc[mi][ni] = (f32x4){0.f, 0.f, 0.f, 0.f};

  for (int k0 = 0; k0 < IN_FEAT; k0 += 32) {
#pragma unroll
    for (int i = 0; i < 2; i++) {
      int cidx = t + i * 256;
      int row = cidx >> 2;
      int ko = (cidx & 3) * 8;
      int gr = m0 + row;
      if (gr > N_NODES - 1) gr = N_NODES - 1;
      const float4* src = (const float4*)&X[(size_t)gr * IN_FEAT + k0 + ko];
      float4 x0 = src[0], x1 = src[1];
      short8x a;
      a[0] = (short)f2bf(x0.x); a[1] = (short)f2bf(x0.y);
      a[2] = (short)f2bf(x0.z); a[3] = (short)f2bf(x0.w);
      a[4] = (short)f2bf(x1.x); a[5] = (short)f2bf(x1.y);
      a[6] = (short)f2bf(x1.z); a[7] = (short)f2bf(x1.w);
      *(short8x*)&As[row * 32 + ko] = a;
    }
#pragma unroll
    for (int i = 0; i < 2; i++) {
      int cidx = t + i * 256;
      int row = cidx >> 2;
      int ko = (cidx & 3) * 8;
      short8x b = *(const short8x*)&Wt[(size_t)(n0 + row) * IN_FEAT + k0 + ko];
      *(short8x*)&Bs[row * 32 + ko] = b;
    }
    __syncthreads();
    short8x af[4], bf[4];
#pragma unroll
    for (int mi = 0; mi < 4; mi++)
      af[mi] = *(const short8x*)&As[(wm + mi * 16 + r) * 32 + q * 8];
#pragma unroll
    for (int ni = 0; ni < 4; ni++)
      bf[ni] = *(const short8x*)&Bs[(wn + ni * 16 + r) * 32 + q * 8];
#pragma unroll
    for (int mi = 0; mi < 4; mi++)
#pragma unroll
      for (int ni = 0; ni < 4; ni++)
        acc[mi][ni] = __builtin_amdgcn_mfma_f32_16x16x32_bf16(af[mi], bf[ni],
                                                              acc[mi][ni], 0, 0, 0);
    __syncthreads();
  }
#pragma unroll
  for (int mi = 0; mi < 4; mi++) {
#pragma unroll
    for (int ni = 0; ni < 4; ni++) {
#pragma unroll
      for (int reg = 0; reg < 4; reg++) {
        int row = m0 + wm + mi * 16 + q * 4 + reg;
        int col = n0 + wn + ni * 16 + r;
        if (row < N_NODES)
          C[(size_t)row * HIDDEN + col] = f2bf(acc[mi][ni][reg]);
      }
    }
  }
}

// ---------------- SpMM1: h = bf16(relu(A @ support1 + b1)) ------------------
__global__ __launch_bounds__(256) void k_spmm1(const unsigned short* __restrict__ S,
                                               const int* __restrict__ rptr,
                                               const int2* __restrict__ sedge,
                                               const float* __restrict__ b1,
                                               unsigned short* __restrict__ H) {
  const int wid = (blockIdx.x * blockDim.x + threadIdx.x) >> 6;  // node
  const int lane = threadIdx.x & 63;
  int e0 = rptr[wid], e1 = rptr[wid + 1];
  float a0 = 0.f, a1 = 0.f, a2 = 0.f, a3 = 0.f;
  for (int base = e0; base < e1; base += 64) {
    int rem = min(64, e1 - base);
    int c = 0;
    float v = 0.f;
    if (lane < rem) {
      int2 e = sedge[base + lane];
      c = e.x;
      v = __int_as_float(e.y);
    }
    for (int j = 0; j < rem; j++) {
      int cj = __shfl(c, j);
      float vj = __shfl(v, j);
      ushort4 s4 = *(const ushort4*)&S[(size_t)cj * HIDDEN + lane * 4];
      a0 += vj * bf2f(s4.x);
      a1 += vj * bf2f(s4.y);
      a2 += vj * bf2f(s4.z);
      a3 += vj * bf2f(s4.w);
    }
  }
  const float4 bb = *(const float4*)&b1[lane * 4];
  ushort4 o;
  o.x = f2bf(fmaxf(a0 + bb.x, 0.f));
  o.y = f2bf(fmaxf(a1 + bb.y, 0.f));
  o.z = f2bf(fmaxf(a2 + bb.z, 0.f));
  o.w = f2bf(fmaxf(a3 + bb.w, 0.f));
  *(ushort4*)&H[(size_t)wid * HIDDEN + lane * 4] = o;
}

// --------------------- GEMM2: support2 = H @ W2 (H bf16) --------------------
__global__ __launch_bounds__(256) void k_gemm2(const unsigned short* __restrict__ H,
                                               const float* __restrict__ W2,
                                               float* __restrict__ S2) {
  __shared__ __align__(16) float Ws[HIDDEN][N_CLASS];  // 40 KB
  __shared__ float Hs[256][33];
  const int t = threadIdx.x;
  const int r0 = blockIdx.x * 256;

#pragma unroll
  for (int i = 0; i < 10; i++) {
    int qq = t + i * 256;
    float4 w = *(const float4*)&W2[(size_t)qq * 4];
    *(float4*)&((float*)Ws)[(size_t)qq * 4] = w;
  }

  float acc[N_CLASS];
#pragma unroll
  for (int n = 0; n < N_CLASS; n++) acc[n] = 0.f;

  for (int kc = 0; kc < HIDDEN; kc += 32) {
    __syncthreads();
    // stage 256 rows x 32 bf16 = 2048 ushort4 chunks, 8 per thread
#pragma unroll
    for (int i = 0; i < 8; i++) {
      int qq = t + i * 256;
      int row = qq >> 3;
      int kv = (qq & 7) * 4;
      int grow = r0 + row;
      if (grow > N_NODES - 1) grow = N_NODES - 1;
      ushort4 hv = *(const ushort4*)&H[(size_t)grow * HIDDEN + kc + kv];
      Hs[row][kv + 0] = bf2f(hv.x);
      Hs[row][kv + 1] = bf2f(hv.y);
      Hs[row][kv + 2] = bf2f(hv.z);
      Hs[row][kv + 3] = bf2f(hv.w);
    }
    __syncthreads();
    const float4* Wsv = (const float4*)Ws;
#pragma unroll
    for (int k = 0; k < 32; k++) {
      float hk = Hs[t][k];
      int kg = kc + k;
#pragma unroll
      for (int n4 = 0; n4 < 10; n4++) {
        float4 w = Wsv[kg * 10 + n4];
        acc[n4 * 4 + 0] += hk * w.x;
        acc[n4 * 4 + 1] += hk * w.y;
        acc[n4 * 4 + 2] += hk * w.z;
        acc[n4 * 4 + 3] += hk * w.w;
      }
    }
  }
  int row = r0 + t;
  if (row < N_NODES) {
#pragma unroll
    for (int n4 = 0; n4 < 10; n4++) {
      float4 o = {acc[n4 * 4 + 0], acc[n4 * 4 + 1], acc[n4 * 4 + 2], acc[n4 * 4 + 3]};
      *(float4*)&S2[(size_t)row * N_CLASS + n4 * 4] = o;
    }
  }
}

// --------- SpMM2 + bias + log_softmax -------------------------------------
__global__ __launch_bounds__(256) void k_spmm2(const float* __restrict__ S2,
                                               const int* __restrict__ rptr,
                                               const int2* __restrict__ sedge,
                                               const float* __restrict__ b2,
                                               float* __restrict__ out) {
  const int wid = (blockIdx.x * blockDim.x + threadIdx.x) >> 6;
  const int lane = threadIdx.x & 63;
  const bool act = lane < N_CLASS;
  const int f = act ? lane : 0;
  int e0 = rptr[wid], e1 = rptr[wid + 1];
  float acc = 0.f;
  for (int base = e0; base < e1; base += 64) {
    int rem = min(64, e1 - base);
    int c = 0;
    float v = 0.f;
    if (lane < rem) {
      int2 e = sedge[base + lane];
      c = e.x;
      v = __int_as_float(e.y);
    }
    for (int j = 0; j < rem; j++) {
      int cj = __shfl(c, j);
      float vj = __shfl(v, j);
      if (act) acc += vj * S2[(size_t)cj * N_CLASS + f];
    }
  }
  float x = act ? (acc + b2[f]) : -INFINITY;
  float m = x;
#pragma unroll
  for (int o = 32; o > 0; o >>= 1) m = fmaxf(m, __shfl_xor(m, o));
  float ex = act ? expf(x - m) : 0.f;
  float s = ex;
#pragma unroll
  for (int o = 32; o > 0; o >>= 1) s += __shfl_xor(s, o);
  if (act) out[(size_t)wid * N_CLASS + lane] = (x - m) - logf(s);
}

// ---------------------------------------------------------------------------
extern "C" void kernel_launch(void* const* d_in, const int* in_sizes, int n_in,
                              void* d_out, int out_size, void* d_ws, size_t ws_size,
                              hipStream_t stream) {
  const float* x    = (const float*)d_in[0];
  const float* w1   = (const float*)d_in[1];
  const float* b1   = (const float*)d_in[2];
  const float* w2   = (const float*)d_in[3];
  const float* b2   = (const float*)d_in[4];
  const float* eval = (const float*)d_in[5];
  const int*   erow = (const int*)d_in[6];
  const int*   ecol = (const int*)d_in[7];
  float* out = (float*)d_out;

  char* ws = (char*)d_ws;
  unsigned short* support1 = (unsigned short*)(ws + OFF_SUPPORT1);
  unsigned short* h        = (unsigned short*)(ws + OFF_H);
  float* support2 = (float*)(ws + OFF_SUPPORT2);
  unsigned short* w1t = (unsigned short*)(ws + OFF_W1T);
  int*   rptr   = (int*)(ws + OFF_RPTR);
  int*   bcnt   = (int*)(ws + OFF_BCNT);
  int*   bbase  = (int*)(ws + OFF_BBASE);
  int*   bcur   = (int*)(ws + OFF_BCUR);
  int2*  binned = (int2*)(ws + OFF_BINNED);
  int2*  sedge  = (int2*)(ws + OFF_SEDGE);

  // ---- CSR build (bucketed) + weight prep ----
  hipMemsetAsync(bcnt, 0, N_BUCKETS * 4, stream);
  k_prep_w<<<512, 256, 0, stream>>>(w1, w1t);
  k_bincnt<<<512, 256, 0, stream>>>(erow, bcnt);
  k_binscan<<<1, 256, 0, stream>>>(bcnt, bbase, bcur, rptr);
  k_binscatter<<<N_SC_BLOCKS, 256, 0, stream>>>(erow, ecol, eval, bcur, binned);
  k_bucket_csr<<<N_BUCKETS, 256, 0, stream>>>(binned, bbase, rptr, sedge);

  // ---- layer 1 ----
  k_gemm1<<<dim3((N_NODES + 127) / 128, HIDDEN / 128), 256, 0, stream>>>(x, w1t, support1);
  k_spmm1<<<N_NODES / 4, 256, 0, stream>>>(support1, rptr, sedge, b1, h);

  // ---- layer 2 ----
  k_gemm2<<<(N_NODES + 255) / 256, 256, 0, stream>>>(h, w2, support2);
  k_spmm2<<<N_NODES / 4, 256, 0, stream>>>(support2, rptr, sedge, b2, out);
}